// Round 1
// baseline (1497.967 us; speedup 1.0000x reference)
//
#include <hip/hip_runtime.h>

// fp32 correctness-first baseline.
// qkv = X @ W^T + b  (GEMM-NT, M=8192 N=3072 K=1024)
// scores = Q @ K^T / 32 per batch -> out1  (GEMM-NT, 2048x2048x1024 x4)
// softmax rows in-place on out1
// out0 = P @ V per batch  (GEMM-NN, 2048x1024x2048 x4)

#define TILE 128
#define BK 16

// C[M,N] = alpha * (A[M,K] @ B[N,K]^T) + bias[N]
// Requires M%128==0, N%128==0, K%16==0, all leading dims multiple of 4.
template <bool HAS_BIAS>
__global__ __launch_bounds__(256) void gemm_nt(
    const float* __restrict__ A, const float* __restrict__ B,
    const float* __restrict__ bias, float* __restrict__ C,
    int K, int lda, int ldb, int ldc,
    long sA, long sB, long sC, float alpha)
{
    A += (long)blockIdx.z * sA;
    B += (long)blockIdx.z * sB;
    C += (long)blockIdx.z * sC;

    __shared__ float As[BK][TILE];
    __shared__ float Bs[BK][TILE];

    const int t  = threadIdx.x;
    const int tx = t & 15;          // 0..15 -> n microtile
    const int ty = t >> 4;          // 0..15 -> m microtile
    const int m0 = blockIdx.y * TILE;
    const int n0 = blockIdx.x * TILE;

    float acc[8][8];
#pragma unroll
    for (int i = 0; i < 8; i++)
#pragma unroll
        for (int j = 0; j < 8; j++) acc[i][j] = 0.f;

    for (int k0 = 0; k0 < K; k0 += BK) {
#pragma unroll
        for (int i = 0; i < 2; i++) {
            int idx = t + i * 256;
            int m  = idx & 127;     // row within tile
            int kb = idx >> 7;      // 0..3 -> which float4 of the 16 k's
            float4 av = *(const float4*)(A + (long)(m0 + m) * lda + k0 + kb * 4);
            As[kb * 4 + 0][m] = av.x;
            As[kb * 4 + 1][m] = av.y;
            As[kb * 4 + 2][m] = av.z;
            As[kb * 4 + 3][m] = av.w;
            float4 bv = *(const float4*)(B + (long)(n0 + m) * ldb + k0 + kb * 4);
            Bs[kb * 4 + 0][m] = bv.x;
            Bs[kb * 4 + 1][m] = bv.y;
            Bs[kb * 4 + 2][m] = bv.z;
            Bs[kb * 4 + 3][m] = bv.w;
        }
        __syncthreads();
#pragma unroll
        for (int kk = 0; kk < BK; kk++) {
            float a[8], bb[8];
            *(float4*)&a[0]  = *(const float4*)&As[kk][ty * 8];
            *(float4*)&a[4]  = *(const float4*)&As[kk][ty * 8 + 4];
            *(float4*)&bb[0] = *(const float4*)&Bs[kk][tx * 8];
            *(float4*)&bb[4] = *(const float4*)&Bs[kk][tx * 8 + 4];
#pragma unroll
            for (int i = 0; i < 8; i++)
#pragma unroll
                for (int j = 0; j < 8; j++) acc[i][j] = fmaf(a[i], bb[j], acc[i][j]);
        }
        __syncthreads();
    }

#pragma unroll
    for (int i = 0; i < 8; i++) {
        long row = m0 + ty * 8 + i;
#pragma unroll
        for (int j = 0; j < 8; j += 4) {
            int n = n0 + tx * 8 + j;
            float4 o;
            o.x = alpha * acc[i][j + 0] + (HAS_BIAS ? bias[n + 0] : 0.f);
            o.y = alpha * acc[i][j + 1] + (HAS_BIAS ? bias[n + 1] : 0.f);
            o.z = alpha * acc[i][j + 2] + (HAS_BIAS ? bias[n + 2] : 0.f);
            o.w = alpha * acc[i][j + 3] + (HAS_BIAS ? bias[n + 3] : 0.f);
            *(float4*)(C + row * ldc + n) = o;
        }
    }
}

// C[M,N] = A[M,K] @ B[K,N]   (both row-major)
__global__ __launch_bounds__(256) void gemm_nn(
    const float* __restrict__ A, const float* __restrict__ B,
    float* __restrict__ C,
    int K, int lda, int ldb, int ldc,
    long sA, long sB, long sC)
{
    A += (long)blockIdx.z * sA;
    B += (long)blockIdx.z * sB;
    C += (long)blockIdx.z * sC;

    __shared__ float As[BK][TILE];
    __shared__ float Bs[BK][TILE];

    const int t  = threadIdx.x;
    const int tx = t & 15;
    const int ty = t >> 4;
    const int m0 = blockIdx.y * TILE;
    const int n0 = blockIdx.x * TILE;

    float acc[8][8];
#pragma unroll
    for (int i = 0; i < 8; i++)
#pragma unroll
        for (int j = 0; j < 8; j++) acc[i][j] = 0.f;

    for (int k0 = 0; k0 < K; k0 += BK) {
#pragma unroll
        for (int i = 0; i < 2; i++) {
            int idx = t + i * 256;
            // A tile: transpose-on-store, same as NT
            int m  = idx & 127;
            int kb = idx >> 7;
            float4 av = *(const float4*)(A + (long)(m0 + m) * lda + k0 + kb * 4);
            As[kb * 4 + 0][m] = av.x;
            As[kb * 4 + 1][m] = av.y;
            As[kb * 4 + 2][m] = av.z;
            As[kb * 4 + 3][m] = av.w;
            // B tile: 16 rows (k) x 128 cols (n), contiguous float4 stores
            int r = idx >> 5;         // 0..15
            int c = (idx & 31) * 4;   // 0..124
            float4 bv = *(const float4*)(B + (long)(k0 + r) * ldb + n0 + c);
            *(float4*)&Bs[r][c] = bv;
        }
        __syncthreads();
#pragma unroll
        for (int kk = 0; kk < BK; kk++) {
            float a[8], bb[8];
            *(float4*)&a[0]  = *(const float4*)&As[kk][ty * 8];
            *(float4*)&a[4]  = *(const float4*)&As[kk][ty * 8 + 4];
            *(float4*)&bb[0] = *(const float4*)&Bs[kk][tx * 8];
            *(float4*)&bb[4] = *(const float4*)&Bs[kk][tx * 8 + 4];
#pragma unroll
            for (int i = 0; i < 8; i++)
#pragma unroll
                for (int j = 0; j < 8; j++) acc[i][j] = fmaf(a[i], bb[j], acc[i][j]);
        }
        __syncthreads();
    }

#pragma unroll
    for (int i = 0; i < 8; i++) {
        long row = m0 + ty * 8 + i;
#pragma unroll
        for (int j = 0; j < 8; j += 4) {
            int n = n0 + tx * 8 + j;
            float4 o;
            o.x = acc[i][j + 0];
            o.y = acc[i][j + 1];
            o.z = acc[i][j + 2];
            o.w = acc[i][j + 3];
            *(float4*)(C + row * ldc + n) = o;
        }
    }
}

// In-place row softmax; ncols == 2048, 256 threads, 8 elements/thread.
__global__ __launch_bounds__(256) void softmax_rows(float* __restrict__ P)
{
    float* row = P + (long)blockIdx.x * 2048;
    const int t = threadIdx.x;
    float4 v0 = *(const float4*)(row + t * 4);
    float4 v1 = *(const float4*)(row + (t + 256) * 4);

    float m = fmaxf(fmaxf(fmaxf(v0.x, v0.y), fmaxf(v0.z, v0.w)),
                    fmaxf(fmaxf(v1.x, v1.y), fmaxf(v1.z, v1.w)));
#pragma unroll
    for (int o = 32; o > 0; o >>= 1) m = fmaxf(m, __shfl_xor(m, o));

    __shared__ float red[4];
    const int wid = t >> 6, lane = t & 63;
    if (lane == 0) red[wid] = m;
    __syncthreads();
    m = fmaxf(fmaxf(red[0], red[1]), fmaxf(red[2], red[3]));
    __syncthreads();

    v0.x = __expf(v0.x - m); v0.y = __expf(v0.y - m);
    v0.z = __expf(v0.z - m); v0.w = __expf(v0.w - m);
    v1.x = __expf(v1.x - m); v1.y = __expf(v1.y - m);
    v1.z = __expf(v1.z - m); v1.w = __expf(v1.w - m);

    float s = (v0.x + v0.y + v0.z + v0.w) + (v1.x + v1.y + v1.z + v1.w);
#pragma unroll
    for (int o = 32; o > 0; o >>= 1) s += __shfl_xor(s, o);
    if (lane == 0) red[wid] = s;
    __syncthreads();
    s = red[0] + red[1] + red[2] + red[3];

    float inv = 1.0f / s;
    v0.x *= inv; v0.y *= inv; v0.z *= inv; v0.w *= inv;
    v1.x *= inv; v1.y *= inv; v1.z *= inv; v1.w *= inv;
    *(float4*)(row + t * 4) = v0;
    *(float4*)(row + (t + 256) * 4) = v1;
}

extern "C" void kernel_launch(void* const* d_in, const int* in_sizes, int n_in,
                              void* d_out, int out_size, void* d_ws, size_t ws_size,
                              hipStream_t stream)
{
    const int B = 4, S = 2048, E = 1024;
    const float* X    = (const float*)d_in[0];   // [B,S,E]
    const float* W    = (const float*)d_in[1];   // [3E,E]
    const float* bias = (const float*)d_in[2];   // [3E]

    float* out0 = (float*)d_out;                       // [B,S,E]
    float* out1 = out0 + (long)B * S * E;              // [B,S,S] attention weights
    float* qkv  = (float*)d_ws;                        // [B*S, 3E] = 96 MB scratch

    // 1) qkv = X @ W^T + b
    gemm_nt<true><<<dim3(3 * E / TILE, B * S / TILE, 1), 256, 0, stream>>>(
        X, W, bias, qkv, E, E, E, 3 * E, 0, 0, 0, 1.0f);

    // 2) scores = Q @ K^T / 32 -> out1 (pre-softmax)
    gemm_nt<false><<<dim3(S / TILE, S / TILE, B), 256, 0, stream>>>(
        qkv + 0, qkv + E, nullptr, out1, E, 3 * E, 3 * E, S,
        (long)S * 3 * E, (long)S * 3 * E, (long)S * S, 0.03125f);

    // 3) softmax in place
    softmax_rows<<<B * S, 256, 0, stream>>>(out1);

    // 4) out0 = P @ V
    gemm_nn<<<dim3(E / TILE, S / TILE, B), 256, 0, stream>>>(
        out1, qkv + 2 * E, out0, S, S, 3 * E, E,
        (long)S * S, (long)S * 3 * E, (long)S * E);
}

// Round 2
// 352.083 us; speedup vs baseline: 4.2546x; 4.2546x over previous
//
#include <hip/hip_runtime.h>
#include <math.h>

typedef __bf16 bf16;
typedef __bf16 bf16x4 __attribute__((ext_vector_type(4)));
typedef __bf16 bf16x8 __attribute__((ext_vector_type(8)));
typedef float f32x4 __attribute__((ext_vector_type(4)));

__device__ inline void gload_lds16(const bf16* g, bf16* l) {
    __builtin_amdgcn_global_load_lds(
        (const __attribute__((address_space(1))) void*)g,
        (__attribute__((address_space(3))) void*)l, 16, 0, 0);
}

// C[M,N] = alpha * (A[M,K] @ B[N,K]^T) (+ bias[N]); A,B bf16 row-major (K contig).
// M%128==0, N%128==0, K%32==0. 256 threads, 4 waves, 128x128 tile, BK=32.
template <typename OutT, bool HAS_BIAS>
__global__ __launch_bounds__(256) void mfma_nt(
    const bf16* __restrict__ A, const bf16* __restrict__ B,
    const float* __restrict__ bias, OutT* __restrict__ C,
    int K, int lda, int ldb, int ldc,
    long sA, long sB, long sC, float alpha)
{
    A += (long)blockIdx.z * sA;
    B += (long)blockIdx.z * sB;
    C += (long)blockIdx.z * sC;

    __shared__ bf16 As[128 * 32] __attribute__((aligned(16)));
    __shared__ bf16 Bs[128 * 32] __attribute__((aligned(16)));

    const int t  = threadIdx.x;
    const int m0 = blockIdx.y * 128;
    const int n0 = blockIdx.x * 128;

    const int lane = t & 63;
    const int wave = t >> 6;
    const int wrow = (wave >> 1) * 64;   // wave's m offset in tile
    const int wcol = (wave & 1) * 64;    // wave's n offset in tile
    const int fr   = lane & 15;          // row/col within 16x16 fragment
    const int kq   = (lane >> 4) * 8;    // k offset for this lane's quad

    // staging: 512 16B-chunks per operand tile; thread t takes chunks t, t+256
    const int r0 = t >> 2,           k80 = (t & 3) * 8;
    const int r1 = (t + 256) >> 2,   k81 = ((t + 256) & 3) * 8;

    f32x4 acc[4][4] = {};

    for (int k0 = 0; k0 < K; k0 += 32) {
        gload_lds16(A + (long)(m0 + r0) * lda + k0 + k80, &As[t * 8]);
        gload_lds16(A + (long)(m0 + r1) * lda + k0 + k81, &As[(t + 256) * 8]);
        gload_lds16(B + (long)(n0 + r0) * ldb + k0 + k80, &Bs[t * 8]);
        gload_lds16(B + (long)(n0 + r1) * ldb + k0 + k81, &Bs[(t + 256) * 8]);
        __syncthreads();

        bf16x8 af[4], bfr[4];
#pragma unroll
        for (int i = 0; i < 4; i++) {
            af[i]  = *(const bf16x8*)&As[(wrow + i * 16 + fr) * 32 + kq];
            bfr[i] = *(const bf16x8*)&Bs[(wcol + i * 16 + fr) * 32 + kq];
        }
#pragma unroll
        for (int i = 0; i < 4; i++)
#pragma unroll
            for (int j = 0; j < 4; j++)
                acc[i][j] = __builtin_amdgcn_mfma_f32_16x16x32_bf16(
                    af[i], bfr[j], acc[i][j], 0, 0, 0);
        __syncthreads();
    }

    // epilogue: C/D layout col=lane&15, row=(lane>>4)*4+reg  [m89-verified]
    const int r4 = (lane >> 4) * 4;
#pragma unroll
    for (int j = 0; j < 4; j++) {
        const int col = n0 + wcol + j * 16 + fr;
        const float bv = HAS_BIAS ? bias[col] : 0.f;
#pragma unroll
        for (int i = 0; i < 4; i++) {
#pragma unroll
            for (int r = 0; r < 4; r++) {
                const long row = m0 + wrow + i * 16 + r4 + r;
                float v = alpha * acc[i][j][r] + bv;
                C[row * ldc + col] = (OutT)v;
            }
        }
    }
}

__global__ __launch_bounds__(256) void f32_to_bf16(
    const float* __restrict__ in, bf16* __restrict__ out, long n)
{
    long i = ((long)blockIdx.x * 256 + threadIdx.x) * 4;
    if (i < n) {
        float4 v = *(const float4*)(in + i);
        bf16x4 o = { (bf16)v.x, (bf16)v.y, (bf16)v.z, (bf16)v.w };
        *(bf16x4*)(out + i) = o;
    }
}

// Vt[b][e][s] = V[b][s][e]; V has ld 3072 (inside qkv), Vt ld 2048.
__global__ __launch_bounds__(256) void transpose_v(
    const bf16* __restrict__ V, bf16* __restrict__ Vt)
{
    __shared__ bf16 tile[32][33];
    const bf16* Vb  = V  + (long)blockIdx.z * 2048 * 3072;
    bf16*       Vtb = Vt + (long)blockIdx.z * 1024 * 2048;
    const int s0 = blockIdx.x * 32, e0 = blockIdx.y * 32;
    const int tx = threadIdx.x & 31, ty = threadIdx.x >> 5;
#pragma unroll
    for (int i = 0; i < 32; i += 8)
        tile[ty + i][tx] = Vb[(long)(s0 + ty + i) * 3072 + e0 + tx];
    __syncthreads();
#pragma unroll
    for (int i = 0; i < 32; i += 8)
        Vtb[(long)(e0 + ty + i) * 2048 + s0 + tx] = tile[tx][ty + i];
}

// In-place fp32 row softmax over 2048 cols + bf16 copy for the PV GEMM.
__global__ __launch_bounds__(256) void softmax_rows(
    float* __restrict__ P, bf16* __restrict__ Pb)
{
    float* row = P + (long)blockIdx.x * 2048;
    bf16* prow = Pb + (long)blockIdx.x * 2048;
    const int t = threadIdx.x;
    float4 v0 = *(const float4*)(row + t * 4);
    float4 v1 = *(const float4*)(row + (t + 256) * 4);

    float m = fmaxf(fmaxf(fmaxf(v0.x, v0.y), fmaxf(v0.z, v0.w)),
                    fmaxf(fmaxf(v1.x, v1.y), fmaxf(v1.z, v1.w)));
#pragma unroll
    for (int o = 32; o > 0; o >>= 1) m = fmaxf(m, __shfl_xor(m, o));

    __shared__ float red[4];
    const int wid = t >> 6, lane = t & 63;
    if (lane == 0) red[wid] = m;
    __syncthreads();
    m = fmaxf(fmaxf(red[0], red[1]), fmaxf(red[2], red[3]));
    __syncthreads();

    v0.x = __expf(v0.x - m); v0.y = __expf(v0.y - m);
    v0.z = __expf(v0.z - m); v0.w = __expf(v0.w - m);
    v1.x = __expf(v1.x - m); v1.y = __expf(v1.y - m);
    v1.z = __expf(v1.z - m); v1.w = __expf(v1.w - m);

    float s = (v0.x + v0.y + v0.z + v0.w) + (v1.x + v1.y + v1.z + v1.w);
#pragma unroll
    for (int o = 32; o > 0; o >>= 1) s += __shfl_xor(s, o);
    if (lane == 0) red[wid] = s;
    __syncthreads();
    s = red[0] + red[1] + red[2] + red[3];

    const float inv = 1.0f / s;
    v0.x *= inv; v0.y *= inv; v0.z *= inv; v0.w *= inv;
    v1.x *= inv; v1.y *= inv; v1.z *= inv; v1.w *= inv;
    *(float4*)(row + t * 4) = v0;
    *(float4*)(row + (t + 256) * 4) = v1;
    bf16x4 p0 = { (bf16)v0.x, (bf16)v0.y, (bf16)v0.z, (bf16)v0.w };
    bf16x4 p1 = { (bf16)v1.x, (bf16)v1.y, (bf16)v1.z, (bf16)v1.w };
    *(bf16x4*)(prow + t * 4) = p0;
    *(bf16x4*)(prow + (t + 256) * 4) = p1;
}

extern "C" void kernel_launch(void* const* d_in, const int* in_sizes, int n_in,
                              void* d_out, int out_size, void* d_ws, size_t ws_size,
                              hipStream_t stream)
{
    const int B = 4, S = 2048, E = 1024;
    const float* X    = (const float*)d_in[0];   // [B,S,E]
    const float* W    = (const float*)d_in[1];   // [3E,E]
    const float* bias = (const float*)d_in[2];   // [3E]

    float* out0 = (float*)d_out;                  // [B,S,E]
    float* out1 = out0 + (long)B * S * E;         // [B,S,S]

    // ws layout (bytes):
    //   [0, 48M)        qkvb bf16 [B*S, 3E]
    //   [48M, 64M)      Vt   bf16 [B][E][S]
    //   [64M, 96M)      Pb   bf16 [B][S][S]   (overlaps Xb/Wb, disjoint lifetime)
    char* ws = (char*)d_ws;
    bf16* qkvb = (bf16*)(ws);
    bf16* Vt   = (bf16*)(ws + 50331648);
    bf16* Pb   = (bf16*)(ws + 67108864);
    bf16* Xb   = (bf16*)(ws + 67108864);           // 16.8 MB, freed before Pb
    bf16* Wb   = (bf16*)(ws + 67108864 + 16777216);// 6.3 MB

    // 1) convert X, W to bf16
    f32_to_bf16<<<(long)B * S * E / 1024, 256, 0, stream>>>(X, Xb, (long)B * S * E);
    f32_to_bf16<<<(long)3 * E * E / 1024, 256, 0, stream>>>(W, Wb, (long)3 * E * E);

    // 2) qkvb = bf16(X @ W^T + b)
    mfma_nt<bf16, true><<<dim3(3 * E / 128, B * S / 128, 1), 256, 0, stream>>>(
        Xb, Wb, bias, qkvb, E, E, E, 3 * E, 0, 0, 0, 1.0f);

    // 3) scores = Q @ K^T / 32 -> out1 (fp32, pre-softmax)
    mfma_nt<float, false><<<dim3(S / 128, S / 128, B), 256, 0, stream>>>(
        qkvb, qkvb + E, nullptr, out1, E, 3 * E, 3 * E, S,
        (long)S * 3 * E, (long)S * 3 * E, (long)S * S, 0.03125f);

    // 4) Vt = V^T per batch
    transpose_v<<<dim3(S / 32, E / 32, B), 256, 0, stream>>>(qkvb + 2 * E, Vt);

    // 5) softmax in place on out1; bf16 copy -> Pb
    softmax_rows<<<B * S, 256, 0, stream>>>(out1, Pb);

    // 6) out0 = P @ V  (= Pb @ Vt^T, NT form)
    mfma_nt<float, false><<<dim3(E / 128, S / 128, B), 256, 0, stream>>>(
        Pb, Vt, nullptr, out0, S, S, S, E,
        (long)S * S, (long)E * S, (long)S * E, 1.0f);
}